// Round 7
// baseline (31802.676 us; speedup 1.0000x reference)
//
#include <hip/hip_runtime.h>
#include <stdint.h>

#define BATCH 256
#define SEQT  512
#define DIM   128
#define HID   256
#define G3    768   // 3*HID

typedef unsigned short u16;
typedef unsigned int   u32;
typedef _Float16 f16;
typedef f16 f16x2 __attribute__((ext_vector_type(2)));
typedef u32 u32x4v __attribute__((ext_vector_type(4)));

static __device__ __forceinline__ u16 f2h(float f) {
  f16 h = (f16)f; return __builtin_bit_cast(u16, h);
}
static __device__ __forceinline__ float h2f(u16 u) {
  return (float)__builtin_bit_cast(f16, u);
}
static __device__ __forceinline__ float sigm(float v) {
  return 1.f / (1.f + __expf(-v));
}

// 2-MAC f16 dot with f32 accumulate
static __device__ __forceinline__ float dot2f(u32 a, u32 b, float acc) {
#if __has_builtin(__builtin_amdgcn_fdot2)
  return __builtin_amdgcn_fdot2(__builtin_bit_cast(f16x2, a),
                                __builtin_bit_cast(f16x2, b), acc, false);
#else
  f16x2 av = __builtin_bit_cast(f16x2, a), bv = __builtin_bit_cast(f16x2, b);
  return acc + (float)av[0] * (float)bv[0] + (float)av[1] * (float)bv[1];
#endif
}
// 8 MACs, dual accumulator
static __device__ __forceinline__ void dot8q(float& a0, float& a1, u32x4v w, u32x4v a) {
  a0 = dot2f(w.x, a.x, a0);
  a1 = dot2f(w.y, a.y, a1);
  a0 = dot2f(w.z, a.z, a0);
  a1 = dot2f(w.w, a.w, a1);
}

// ---------------- weight fp32 -> f16, quad chunk-major layout ----------------
// dst[(((g*CH + jj)*256 + c)*4 + sub)*8 + e] = f16( src[(g*256+c)*IN + sub*(IN/4) + jj*8 + e] )
__global__ void convertQ(const float* __restrict__ src, u16* __restrict__ dst,
                         int IN, int CH, int total) {
  int t = blockIdx.x * 256 + threadIdx.x;
  if (t >= total) return;
  int e = t & 7, sub = (t >> 3) & 3, c = (t >> 5) & 255;
  int qq = t >> 13;
  int jj = qq % CH, g = qq / CH;
  int col = sub * (IN / 4) + jj * 8 + e;
  dst[t] = f2h(src[(size_t)(g * 256 + c) * IN + col]);
}

// ---------------- phase B: memory GRU, quad-split, 1024 threads, 1 block/row ----------------
__launch_bounds__(1024)
__global__ void gru_memq(const float* __restrict__ x,
                         const u16* __restrict__ WiT, const u16* __restrict__ WhT,
                         const float* __restrict__ bmi, const float* __restrict__ bmh,
                         u16* __restrict__ mem) {
  const int b = blockIdx.x, tid = threadIdx.x;
  const int c = tid >> 2, sub = tid & 3;
  __shared__ __align__(16) u16 xsH[DIM];
  __shared__ __align__(16) u16 hsH[HID];

  const float Brzr = bmi[c] + bmh[c];
  const float Brzz = bmi[HID + c] + bmh[HID + c];
  const float Bni  = bmi[2*HID + c];
  const float Bnh  = bmh[2*HID + c];
  const u32x4v* Wi4 = (const u32x4v*)WiT;   // CH=4
  const u32x4v* Wh4 = (const u32x4v*)WhT;   // CH=8
  const int widx = (c << 2) + sub;
  float hprev = 0.f;
  if (tid < HID) hsH[tid] = 0;
  __syncthreads();

  for (int t = 0; t < SEQT; ++t) {
    if (tid < DIM)
      xsH[tid] = f2h(__builtin_nontemporal_load(x + ((size_t)b * SEQT + t) * DIM + tid));
    __syncthreads();               // S_a: xsH ready; hsH writes visible
    float ar0=0.f, ar1=0.f, az0=0.f, az1=0.f, axn0=0.f, axn1=0.f, ahn0=0.f, ahn1=0.f;
    const u32x4v* xs4 = (const u32x4v*)xsH;
    const u32x4v* hs4 = (const u32x4v*)hsH;
    #pragma unroll
    for (int jj = 0; jj < 4; ++jj) {
      u32x4v av = xs4[sub * 4 + jj];
      dot8q(ar0, ar1, Wi4[((0*4 + jj) << 10) + widx], av);
      dot8q(az0, az1, Wi4[((1*4 + jj) << 10) + widx], av);
      dot8q(axn0, axn1, Wi4[((2*4 + jj) << 10) + widx], av);
    }
    #pragma unroll 4
    for (int jj = 0; jj < 8; ++jj) {
      u32x4v av = hs4[sub * 8 + jj];
      dot8q(ar0, ar1, Wh4[((0*8 + jj) << 10) + widx], av);
      dot8q(az0, az1, Wh4[((1*8 + jj) << 10) + widx], av);
      dot8q(ahn0, ahn1, Wh4[((2*8 + jj) << 10) + widx], av);
    }
    float ar = ar0 + ar1, az = az0 + az1, axn = axn0 + axn1, ahn = ahn0 + ahn1;
    ar  += __shfl_xor(ar, 1);  ar  += __shfl_xor(ar, 2);
    az  += __shfl_xor(az, 1);  az  += __shfl_xor(az, 2);
    axn += __shfl_xor(axn, 1); axn += __shfl_xor(axn, 2);
    ahn += __shfl_xor(ahn, 1); ahn += __shfl_xor(ahn, 2);
    __syncthreads();               // S_b: all reads of hsH done
    if (sub == 0) {
      float r = sigm(ar + Brzr);
      float z = sigm(az + Brzz);
      float nn = tanhf(axn + Bni + r * (ahn + Bnh));
      float h = (1.f - z) * nn + z * hprev;
      hprev = h;
      hsH[c] = f2h(h);
      mem[((size_t)b * SEQT + t) * HID + c] = f2h(h);
    }
  }
}

// ---------------- decoder quad cell: all 3 gates per quad, 1 sync ----------------
template <int IN>
static __device__ __forceinline__ void cellQ(const u16* __restrict__ inH,
                                             u16* __restrict__ outH,
                                             const u16* __restrict__ WT,
                                             int c, int sub,
                                             float Brzr, float Brzz, float Bni, float Bnh) {
  constexpr int CH = IN / 32;
  const u32x4v* W4 = (const u32x4v*)WT;
  const u32x4v* in4 = (const u32x4v*)inH;
  const int widx = (c << 2) + sub;
  float ar0=0.f, ar1=0.f, az0=0.f, az1=0.f, an0=0.f, an1=0.f;
  #pragma unroll 4
  for (int jj = 0; jj < CH; ++jj) {
    u32x4v av = in4[sub * CH + jj];
    dot8q(ar0, ar1, W4[((0*CH + jj) << 10) + widx], av);
    dot8q(az0, az1, W4[((1*CH + jj) << 10) + widx], av);
    dot8q(an0, an1, W4[((2*CH + jj) << 10) + widx], av);
  }
  float ar = ar0 + ar1, az = az0 + az1, an = an0 + an1;
  ar += __shfl_xor(ar, 1); ar += __shfl_xor(ar, 2);
  az += __shfl_xor(az, 1); az += __shfl_xor(az, 2);
  an += __shfl_xor(an, 1); an += __shfl_xor(an, 2);
  if (sub == 0) {
    float r = sigm(ar + Brzr);
    float z = sigm(az + Brzz);
    float nn = tanhf(an + Bni + r * Bnh);
    outH[c] = f2h((1.f - z) * nn);
  }
  __syncthreads();
}

// ---------------- phase C: decoder scan, 1024 threads, 1 block/row ----------------
__launch_bounds__(1024)
__global__ void decoderq(const float* __restrict__ x, const u16* __restrict__ memH,
                         const u16* __restrict__ W0T, const u16* __restrict__ W1T,
                         const u16* __restrict__ W2T, const u16* __restrict__ W3T,
                         const u16* __restrict__ W4T,
                         const float* __restrict__ bi0, const float* __restrict__ bh0,
                         const float* __restrict__ bi1, const float* __restrict__ bh1,
                         const float* __restrict__ bi2, const float* __restrict__ bh2,
                         const float* __restrict__ bi3, const float* __restrict__ bh3,
                         const float* __restrict__ bi4, const float* __restrict__ bh4,
                         const float* __restrict__ Wo, const float* __restrict__ bo,
                         float* __restrict__ out) {
  const int b = blockIdx.x, tid = threadIdx.x;
  const int lane = tid & 63, wave = tid >> 6;
  const int c = tid >> 2, sub = tid & 3;
  __shared__ __align__(16) u16 kstH[HID];
  __shared__ __align__(16) u16 dvH[DIM + HID];
  __shared__ __align__(16) u16 hAH[HID], hBH[HID];
  __shared__ __align__(16) float ppF[512];
  __shared__ __align__(16) float pvp[8][HID];
  __shared__ float red[16], red2[16];

  // per-column biases (rows c, 256+c, 512+c of each cell)
  float Rr[5], Rz[5], Ni[5], Nh[5];
  Rr[0]=bi0[c]+bh0[c]; Rz[0]=bi0[HID+c]+bh0[HID+c]; Ni[0]=bi0[2*HID+c]; Nh[0]=bh0[2*HID+c];
  Rr[1]=bi1[c]+bh1[c]; Rz[1]=bi1[HID+c]+bh1[HID+c]; Ni[1]=bi1[2*HID+c]; Nh[1]=bh1[2*HID+c];
  Rr[2]=bi2[c]+bh2[c]; Rz[2]=bi2[HID+c]+bh2[HID+c]; Ni[2]=bi2[2*HID+c]; Nh[2]=bh2[2*HID+c];
  Rr[3]=bi3[c]+bh3[c]; Rz[3]=bi3[HID+c]+bh3[HID+c]; Ni[3]=bi3[2*HID+c]; Nh[3]=bh3[2*HID+c];
  Rr[4]=bi4[c]+bh4[c]; Rz[4]=bi4[HID+c]+bh4[HID+c]; Ni[4]=bi4[2*HID+c]; Nh[4]=bh4[2*HID+c];
  float wo0 = 0.f, wo1 = 0.f, wo2 = 0.f, wo3 = 0.f;
  const float bo0 = bo[0];
  if (wave == 0) { wo0 = Wo[lane]; wo1 = Wo[64+lane]; wo2 = Wo[128+lane]; wo3 = Wo[192+lane]; }
  if (tid < HID) kstH[tid] = 0;
  __syncthreads();

  const u16* mb = memH + (size_t)b * SEQT * HID;
  const int p = tid >> 1, hf = tid & 1;      // scores
  const int sg = tid >> 7, cp = tid & 127;   // PV

  for (int t = 0; t < SEQT; ++t) {
    float xr = 0.f;
    if (tid < DIM)
      xr = __builtin_nontemporal_load(x + ((size_t)b * SEQT + t) * DIM + tid);

    // ---- scores: thread = (position p, half hf) ----
    float s0 = 0.f, s1 = 0.f;
    {
      const u32x4v* mr = (const u32x4v*)(mb + (size_t)p * HID) + hf * 16;
      const u32x4v* kq = ((const u32x4v*)kstH) + hf * 16;
      #pragma unroll 8
      for (int j = 0; j < 16; ++j) dot8q(s0, s1, mr[j], kq[j]);
    }
    float s = s0 + s1;
    s += __shfl_xor(s, 1);
    float mloc = s;
    #pragma unroll
    for (int off = 32; off; off >>= 1) mloc = fmaxf(mloc, __shfl_xor(mloc, off));
    if (lane == 0) red[wave] = mloc;
    __syncthreads();               // S1
    float m = red[0];
    #pragma unroll
    for (int i = 1; i < 16; ++i) m = fmaxf(m, red[i]);
    float pw = __expf(s - m);
    if (!hf) ppF[p] = pw;
    float ls = hf ? 0.f : pw;
    #pragma unroll
    for (int off = 32; off; off >>= 1) ls += __shfl_xor(ls, off);
    if (lane == 0) red2[wave] = ls;
    if (tid < DIM) dvH[tid] = f2h(xr);
    __syncthreads();               // S2

    // ---- PV: thread = (s-eighth sg, column pair cp) ----
    float c0 = 0.f, c1 = 0.f;
    {
      const u32* mc = (const u32*)mb + (size_t)sg * 64 * 128 + cp;
      const float* ppg = ppF + sg * 64;
      #pragma unroll 8
      for (int pj = 0; pj < 64; ++pj) {
        u32 v = mc[(size_t)pj * 128];
        float w2 = ppg[pj];
        f16x2 hv = __builtin_bit_cast(f16x2, v);
        c0 += w2 * (float)hv[0];
        c1 += w2 * (float)hv[1];
      }
      pvp[sg][2 * cp]     = c0;
      pvp[sg][2 * cp + 1] = c1;
    }
    __syncthreads();               // S3
    if (tid < HID) {
      float lsum = red2[0];
      #pragma unroll
      for (int i = 1; i < 16; ++i) lsum += red2[i];
      float ctx = pvp[0][tid] + pvp[1][tid] + pvp[2][tid] + pvp[3][tid] +
                  pvp[4][tid] + pvp[5][tid] + pvp[6][tid] + pvp[7][tid];
      dvH[DIM + tid] = f2h(ctx / lsum);
    }
    __syncthreads();               // S4

    // ---- 5 quad-split feed-forward GRU cells (1 sync each) ----
    cellQ<DIM + HID>(dvH, hAH, W0T, c, sub, Rr[0], Rz[0], Ni[0], Nh[0]);
    cellQ<HID>(hAH, hBH, W1T, c, sub, Rr[1], Rz[1], Ni[1], Nh[1]);
    cellQ<HID>(hBH, hAH, W2T, c, sub, Rr[2], Rz[2], Ni[2], Nh[2]);
    cellQ<HID>(hAH, hBH, W3T, c, sub, Rr[3], Rz[3], Ni[3], Nh[3]);
    cellQ<HID>(hBH, kstH, W4T, c, sub, Rr[4], Rz[4], Ni[4], Nh[4]);

    // ---- output layer (wave 0) ----
    if (wave == 0) {
      float acc = h2f(kstH[lane]) * wo0 + h2f(kstH[64 + lane]) * wo1 +
                  h2f(kstH[128 + lane]) * wo2 + h2f(kstH[192 + lane]) * wo3;
      #pragma unroll
      for (int off = 32; off; off >>= 1) acc += __shfl_xor(acc, off);
      if (lane == 0) out[(size_t)b * SEQT + t] = sigm(acc + bo0);
    }
  }
}

// ---------------- host ----------------
extern "C" void kernel_launch(void* const* d_in, const int* in_sizes, int n_in,
                              void* d_out, int out_size, void* d_ws, size_t ws_size,
                              hipStream_t stream) {
  const float* x    = (const float*)d_in[0];
  const float* Wmi  = (const float*)d_in[1];
  const float* Wmh  = (const float*)d_in[2];
  const float* bmi  = (const float*)d_in[3];
  const float* bmh  = (const float*)d_in[4];
  const float* Wd0  = (const float*)d_in[5];
  const float* bi0  = (const float*)d_in[6];
  const float* bh0  = (const float*)d_in[7];
  const float* Wd1  = (const float*)d_in[8];
  const float* bi1  = (const float*)d_in[9];
  const float* bh1  = (const float*)d_in[10];
  const float* Wd2  = (const float*)d_in[11];
  const float* bi2  = (const float*)d_in[12];
  const float* bh2  = (const float*)d_in[13];
  const float* Wk0  = (const float*)d_in[14];
  const float* bik0 = (const float*)d_in[15];
  const float* bhk0 = (const float*)d_in[16];
  const float* Wk1  = (const float*)d_in[17];
  const float* bik1 = (const float*)d_in[18];
  const float* bhk1 = (const float*)d_in[19];
  const float* Wo   = (const float*)d_in[20];
  const float* bo   = (const float*)d_in[21];

  u16* mem = (u16*)d_ws;
  size_t off = (size_t)BATCH * SEQT * HID;     // u16 units
  u16* WmiT = mem + off; off += (size_t)G3 * DIM;
  u16* WmhT = mem + off; off += (size_t)G3 * HID;
  u16* W0T  = mem + off; off += (size_t)G3 * (DIM + HID);
  u16* W1T  = mem + off; off += (size_t)G3 * HID;
  u16* W2T  = mem + off; off += (size_t)G3 * HID;
  u16* W3T  = mem + off; off += (size_t)G3 * HID;
  u16* W4T  = mem + off; off += (size_t)G3 * HID;
  (void)ws_size; (void)in_sizes; (void)n_in; (void)out_size;

  // quad chunk-major f16 weight transposes
  convertQ<<<(G3*DIM + 255) / 256, 256, 0, stream>>>(Wmi, WmiT, DIM, DIM/32, G3*DIM);
  convertQ<<<(G3*HID + 255) / 256, 256, 0, stream>>>(Wmh, WmhT, HID, HID/32, G3*HID);
  convertQ<<<(G3*(DIM+HID) + 255) / 256, 256, 0, stream>>>(Wd0, W0T, DIM+HID, (DIM+HID)/32, G3*(DIM+HID));
  convertQ<<<(G3*HID + 255) / 256, 256, 0, stream>>>(Wd1, W1T, HID, HID/32, G3*HID);
  convertQ<<<(G3*HID + 255) / 256, 256, 0, stream>>>(Wd2, W2T, HID, HID/32, G3*HID);
  convertQ<<<(G3*HID + 255) / 256, 256, 0, stream>>>(Wk0, W3T, HID, HID/32, G3*HID);
  convertQ<<<(G3*HID + 255) / 256, 256, 0, stream>>>(Wk1, W4T, HID, HID/32, G3*HID);

  gru_memq<<<BATCH, 1024, 0, stream>>>(x, WmiT, WmhT, bmi, bmh, mem);
  decoderq<<<BATCH, 1024, 0, stream>>>(x, mem, W0T, W1T, W2T, W3T, W4T,
                                       bi0, bh0, bi1, bh1, bi2, bh2,
                                       bik0, bhk0, bik1, bhk1, Wo, bo,
                                       (float*)d_out);
}